// Round 1
// baseline (699.487 us; speedup 1.0000x reference)
//
#include <hip/hip_runtime.h>

#define T_ 512
#define B_ 2048
#define ROWP 12   // padded floats per sequence row (10 used + 2 pad) -> 48B, 16B-aligned

__device__ __forceinline__ float sigm2(float y) {
  // 1 / (1 + exp2(y)); caller pre-scales y = -x*log2e (sigmoid) or -2x*log2e (tanh)
  return __builtin_amdgcn_rcpf(1.0f + __builtin_amdgcn_exp2f(y));
}

template<int CTRL>
__device__ __forceinline__ float qb(float v) {
  // quad_perm DPP broadcast of lane (CTRL/0x55) within each 4-lane quad
  return __int_as_float(__builtin_amdgcn_mov_dpp(__float_as_int(v), CTRL, 0xF, 0xF, true));
}

template<int W>
__device__ __forceinline__ void loadrow(float* xv, const float* p) {
  if constexpr (W == 2) {
    const float2 v = *(const float2*)p;
    xv[0] = v.x; xv[1] = v.y;
  } else {
    const float4 a = *(const float4*)p;
    const float4 b = *(const float4*)(p + 4);
    const float2 c = *(const float2*)(p + 8);
    xv[0]=a.x; xv[1]=a.y; xv[2]=a.z; xv[3]=a.w;
    xv[4]=b.x; xv[5]=b.y; xv[6]=b.z; xv[7]=b.w;
    xv[8]=c.x; xv[9]=c.y;
  }
}

// One LSTM cell step. Lane q=4u+g of a 20-lane group owns gate g (0=i,1=f,2=g,3=o)
// of hidden unit u, i.e. row g*5+u of the 20x(in+H) gate matrix.
template<int W>
__device__ __forceinline__ void cell_step(const float* xv, const float* wi,
    const float* wh, float bb, float kmul, float vm, float va,
    const int* pidx, float& c, float& h, float* hall)
{
  float acc = bb;
  #pragma unroll
  for (int k = 0; k < W; ++k) acc = fmaf(wi[k], xv[k], acc);
  #pragma unroll
  for (int u = 0; u < 5; ++u) acc = fmaf(wh[u], hall[u], acc);
  const float s   = sigm2(acc * kmul);
  const float val = fmaf(s, vm, va);          // sigmoid, or tanh = 2*sigm(2x)-1
  const float iv = qb<0x00>(val);
  const float fv = qb<0x55>(val);
  const float gv = qb<0xAA>(val);
  const float ov = qb<0xFF>(val);
  c = fmaf(fv, c, iv * gv);
  const float tc = fmaf(sigm2(c * -2.8853900817779268f), 2.0f, -1.0f);  // tanh(c)
  h = ov * tc;
  const int hb = __float_as_int(h);
  #pragma unroll
  for (int u = 0; u < 5; ++u)
    hall[u] = __int_as_float(__builtin_amdgcn_ds_bpermute(pidx[u], hb));
}

// Full scan over T_ steps for one (batch, direction), 4-deep input prefetch.
template<int W, bool STORE>
__device__ __forceinline__ float scan_one(const float* src0, int sstep,
    float* dst0, int dstep, bool doStore,
    const float* wi, const float* wh, float bb,
    float kmul, float vm, float va, const int* pidx)
{
  float xa[W], xb[W], xc[W], xd[W];
  loadrow<W>(xa, src0);
  loadrow<W>(xb, src0 + sstep);
  loadrow<W>(xc, src0 + 2 * sstep);
  loadrow<W>(xd, src0 + 3 * sstep);
  const float* lp = src0 + 4 * sstep;
  float c = 0.f, h = 0.f;
  float hall[5] = {0.f, 0.f, 0.f, 0.f, 0.f};
  float* dp = dst0;
  for (int tt = 0; tt < T_; tt += 4) {
    cell_step<W>(xa, wi, wh, bb, kmul, vm, va, pidx, c, h, hall);
    if constexpr (STORE) { if (doStore) *dp = h; dp += dstep; }
    if (tt + 4 < T_) { loadrow<W>(xa, lp); lp += sstep; }

    cell_step<W>(xb, wi, wh, bb, kmul, vm, va, pidx, c, h, hall);
    if constexpr (STORE) { if (doStore) *dp = h; dp += dstep; }
    if (tt + 5 < T_) { loadrow<W>(xb, lp); lp += sstep; }

    cell_step<W>(xc, wi, wh, bb, kmul, vm, va, pidx, c, h, hall);
    if constexpr (STORE) { if (doStore) *dp = h; dp += dstep; }
    if (tt + 6 < T_) { loadrow<W>(xc, lp); lp += sstep; }

    cell_step<W>(xd, wi, wh, bb, kmul, vm, va, pidx, c, h, hall);
    if constexpr (STORE) { if (doStore) *dp = h; dp += dstep; }
    if (tt + 7 < T_) { loadrow<W>(xd, lp); lp += sstep; }
  }
  return h;
}

__global__ __launch_bounds__(256) void lstm_all(
    const float* __restrict__ x, const float* __restrict__ Wih0,
    const float* __restrict__ Wih, const float* __restrict__ Whh,
    const float* __restrict__ bias, const float* __restrict__ Wfc,
    const float* __restrict__ bfc, float* __restrict__ out,
    float* __restrict__ ws, int b0, int nb)
{
  __shared__ float hlast[6][2][5];   // per-block: 6 batch x 2 dirs x H

  const int tid  = threadIdx.x;
  const int lane = tid & 63;
  const int wave = tid >> 6;
  const int giw  = lane / 20;          // group within wave: 0..2 (3 = idle lanes 60-63)
  const int q    = lane % 20;
  const int u    = q >> 2;
  const int g    = q & 3;
  const int row  = g * 5 + u;          // gate-matrix row (i:0-4, f:5-9, g:10-14, o:15-19)
  const int gl   = wave * 3 + (giw < 3 ? giw : 2);
  const int gid  = blockIdx.x * 12 + gl;
  const bool grpactive = (giw < 3) && (gid < 2 * nb);
  const int d    = gid & 1;
  const int bloc = gid >> 1;
  const int blocsafe = (bloc < nb) ? bloc : (nb - 1);
  const int babs = b0 + blocsafe;      // absolute batch index

  const int grpbase = (lane / 20) * 20;
  int pidx[5];
  #pragma unroll
  for (int k = 0; k < 5; ++k) pidx[k] = (grpbase + 4 * k) << 2;

  const float LOG2E = 1.4426950408889634f;
  const float kmul = (g == 2) ? (-2.0f * LOG2E) : (-LOG2E);
  const float vm   = (g == 2) ? 2.0f : 1.0f;
  const float va   = (g == 2) ? -1.0f : 0.0f;

  float* S0 = ws;
  float* S1 = ws + (size_t)nb * T_ * ROWP;

  const bool doStore = (g == 0) && grpactive;
  const size_t rowbase = (size_t)blocsafe * T_ * ROWP;
  const size_t t0off   = d ? (size_t)(T_ - 1) * ROWP : 0;
  const int sstep = d ? -ROWP : ROWP;
  const int dcol  = d * 5 + u;

  float wh[5], bb;

  // ---------------- layer 0 (input width 2) ----------------
  {
    float wi[2];
    const float* Wip = Wih0 + ((size_t)d * 20 + row) * 2;
    wi[0] = Wip[0]; wi[1] = Wip[1];
    const float* Whp = Whh + ((size_t)d * 20 + row) * 5;
    #pragma unroll
    for (int k = 0; k < 5; ++k) wh[k] = Whp[k];
    bb = bias[(size_t)d * 20 + row];
    const float* src0 = x + ((size_t)babs * T_ + (d ? (T_ - 1) : 0)) * 2;
    scan_one<2, true>(src0, d ? -2 : 2,
                      S0 + rowbase + t0off + dcol, sstep, doStore,
                      wi, wh, bb, kmul, vm, va, pidx);
  }
  __syncthreads();

  // ---------------- layers 1..3 (input width 10) ----------------
  for (int l = 1; l < 4; ++l) {
    float wi[10];
    const float* Wip = Wih + (((size_t)(l - 1) * 2 + d) * 20 + row) * 10;
    #pragma unroll
    for (int k = 0; k < 10; ++k) wi[k] = Wip[k];
    const float* Whp = Whh + (((size_t)l * 2 + d) * 20 + row) * 5;
    #pragma unroll
    for (int k = 0; k < 5; ++k) wh[k] = Whp[k];
    bb = bias[((size_t)l * 2 + d) * 20 + row];
    const float* src = (l & 1) ? S0 : S1;
    float*       dst = (l & 1) ? S1 : S0;
    scan_one<10, true>(src + rowbase + t0off, sstep,
                       dst + rowbase + t0off + dcol, sstep, doStore,
                       wi, wh, bb, kmul, vm, va, pidx);
    __syncthreads();
  }

  // ---------------- layer 4: fwd = full scan (no stores); bwd = 1 step at t=T-1 ----------------
  {
    float wi[10];
    const float* Wip = Wih + (((size_t)3 * 2 + d) * 20 + row) * 10;
    #pragma unroll
    for (int k = 0; k < 10; ++k) wi[k] = Wip[k];
    const float* Whp = Whh + (((size_t)4 * 2 + d) * 20 + row) * 5;
    #pragma unroll
    for (int k = 0; k < 5; ++k) wh[k] = Whp[k];
    bb = bias[((size_t)4 * 2 + d) * 20 + row];

    float hfin;
    if (d == 0) {
      hfin = scan_one<10, false>(S1 + rowbase, ROWP, nullptr, 0, false,
                                 wi, wh, bb, kmul, vm, va, pidx);
    } else {
      float xs[10];
      loadrow<10>(xs, S1 + rowbase + (size_t)(T_ - 1) * ROWP);
      float cc = 0.f, hh = 0.f;
      float hall0[5] = {0.f, 0.f, 0.f, 0.f, 0.f};
      cell_step<10>(xs, wi, wh, bb, kmul, vm, va, pidx, cc, hh, hall0);
      hfin = hh;
    }
    if (doStore) hlast[gl >> 1][d][u] = hfin;
  }
  __syncthreads();

  // ---------------- fused FC: out[b] = hlast[b] @ Wfc^T + bfc ----------------
  if (tid < 12) {
    const int bl = tid >> 1, o = tid & 1;
    if (blockIdx.x * 6 + bl < nb) {
      const int gb = b0 + blockIdx.x * 6 + bl;
      float a = bfc[o];
      #pragma unroll
      for (int cix = 0; cix < 10; ++cix)
        a = fmaf(hlast[bl][cix / 5][cix % 5], Wfc[o * 10 + cix], a);
      out[gb * 2 + o] = a;
    }
  }
}

extern "C" void kernel_launch(void* const* d_in, const int* in_sizes, int n_in,
                              void* d_out, int out_size, void* d_ws, size_t ws_size,
                              hipStream_t stream) {
  (void)in_sizes; (void)n_in; (void)out_size;
  const float* x    = (const float*)d_in[0];
  const float* Wih0 = (const float*)d_in[1];
  const float* Wih  = (const float*)d_in[2];
  const float* Whh  = (const float*)d_in[3];
  const float* bias = (const float*)d_in[4];
  const float* Wfc  = (const float*)d_in[5];
  const float* bfc  = (const float*)d_in[6];
  float* out = (float*)d_out;
  float* ws  = (float*)d_ws;

  // Chunk the batch if ws can't hold 2 ping-pong buffers of [nb][T][ROWP] f32.
  const size_t perBatch = (size_t)2 * T_ * ROWP * sizeof(float);  // 49152 B
  int nbmax = (int)(ws_size / perBatch);
  if (nbmax > B_) nbmax = B_;
  if (nbmax < 1)  nbmax = 1;

  for (int b0 = 0; b0 < B_; b0 += nbmax) {
    int nb = B_ - b0 < nbmax ? B_ - b0 : nbmax;
    dim3 grid((2 * nb + 11) / 12);
    dim3 block(256);
    lstm_all<<<grid, block, 0, stream>>>(x, Wih0, Wih, Whh, bias, Wfc, bfc,
                                         out, ws, b0, nb);
  }
}

// Round 2
// 613.946 us; speedup vs baseline: 1.1393x; 1.1393x over previous
//
#include <hip/hip_runtime.h>

#define T_ 512
#define B_ 2048
// Packed inter-layer row: 6 dwords = 12 bf16 (24B). dir d owns dwords 3d..3d+2
// = bf16 cols 6d+0..4 (col 6d+5 is zero pad). h stays f32 inside a layer; only
// the inter-layer handoff is rounded to bf16 (RNE).
#define ROWDW 6

__device__ __forceinline__ float sigm2(float y) {
  // 1 / (1 + exp2(y)); caller pre-scales y = -x*log2e (sigmoid) or -2x*log2e (tanh)
  return __builtin_amdgcn_rcpf(1.0f + __builtin_amdgcn_exp2f(y));
}

template<int CTRL>
__device__ __forceinline__ float qb(float v) {
  // quad_perm DPP broadcast of one lane within each 4-lane quad
  return __int_as_float(__builtin_amdgcn_mov_dpp(__float_as_int(v), CTRL, 0xF, 0xF, true));
}

__device__ __forceinline__ unsigned bfr(float f) {   // f32 -> bf16 bits, RNE
  unsigned u = __float_as_uint(f);
  return (u + 0x7FFFu + ((u >> 16) & 1u)) >> 16;
}

struct RowP { unsigned d[6]; };

__device__ __forceinline__ RowP loadrow_p(const unsigned* p) {
  RowP r;
  const uint2 a = *(const uint2*)p;
  const uint2 b = *(const uint2*)(p + 2);
  const uint2 c = *(const uint2*)(p + 4);
  r.d[0]=a.x; r.d[1]=a.y; r.d[2]=b.x; r.d[3]=b.y; r.d[4]=c.x; r.d[5]=c.y;
  return r;
}

__device__ __forceinline__ void unpack_row(const RowP& r, float* xv) {
  #pragma unroll
  for (int k = 0; k < 6; ++k) {
    xv[2*k]   = __int_as_float((int)(r.d[k] << 16));
    xv[2*k+1] = __int_as_float((int)(r.d[k] & 0xFFFF0000u));
  }
}

// One LSTM cell step. Lane q=4u+g of a 20-lane group owns gate g (0=i,1=f,2=g,3=o)
// of hidden unit u, i.e. row g*5+u of the 20x(in+H) gate matrix.
template<int W>
__device__ __forceinline__ void cell_step(const float* xv, const float* wi,
    const float* wh, float bb, float kmul, float vm, float va,
    const int* pidx, float& c, float& h, float* hall)
{
  float acc = bb;
  #pragma unroll
  for (int k = 0; k < W; ++k) acc = fmaf(wi[k], xv[k], acc);
  #pragma unroll
  for (int u = 0; u < 5; ++u) acc = fmaf(wh[u], hall[u], acc);
  const float s   = sigm2(acc * kmul);
  const float val = fmaf(s, vm, va);          // sigmoid, or tanh = 2*sigm(2x)-1
  const float iv = qb<0x00>(val);
  const float fv = qb<0x55>(val);
  const float gv = qb<0xAA>(val);
  const float ov = qb<0xFF>(val);
  c = fmaf(fv, c, iv * gv);
  const float tc = fmaf(sigm2(c * -2.8853900817779268f), 2.0f, -1.0f);  // tanh(c)
  h = ov * tc;
  const int hb = __float_as_int(h);
  #pragma unroll
  for (int u = 0; u < 5; ++u)
    hall[u] = __int_as_float(__builtin_amdgcn_ds_bpermute(pidx[u], hb));
}

__device__ __forceinline__ void store_row(unsigned* dp, const float* hall) {
  dp[0] = bfr(hall[0]) | (bfr(hall[1]) << 16);
  dp[1] = bfr(hall[2]) | (bfr(hall[3]) << 16);
  dp[2] = bfr(hall[4]);      // high half = 0 pad (zero-weighted by reader anyway)
}

// Layer-0 scan: reads f32 x (width 2), writes packed rows. 8-deep prefetch.
__device__ __forceinline__ void scan_l0(const float* src0, int sstep,
    unsigned* dst0, int dstep, bool doStore,
    const float* wi, const float* wh, float bb,
    float kmul, float vm, float va, const int* pidx)
{
  float2 p[8];
  #pragma unroll
  for (int k = 0; k < 8; ++k) p[k] = *(const float2*)(src0 + k * sstep);
  const float* lp = src0 + 8 * sstep;
  float c = 0.f, h = 0.f;
  float hall[5] = {0.f, 0.f, 0.f, 0.f, 0.f};
  unsigned* dp = dst0;
  for (int tt = 0; tt < T_ - 8; tt += 8) {
    #pragma unroll
    for (int j = 0; j < 8; ++j) {
      float xv[2] = {p[j].x, p[j].y};
      cell_step<2>(xv, wi, wh, bb, kmul, vm, va, pidx, c, h, hall);
      if (doStore) store_row(dp, hall);
      dp += dstep;
      p[j] = *(const float2*)lp; lp += sstep;
    }
  }
  #pragma unroll
  for (int j = 0; j < 8; ++j) {
    float xv[2] = {p[j].x, p[j].y};
    cell_step<2>(xv, wi, wh, bb, kmul, vm, va, pidx, c, h, hall);
    if (doStore) store_row(dp, hall);
    dp += dstep;
  }
}

// Packed-input scan (layers 1..4): reads 24B rows, 8-deep prefetch.
template<bool STORE>
__device__ __forceinline__ float scan_packed(const unsigned* src0, int sstep,
    unsigned* dst0, int dstep, bool doStore,
    const float* wi, const float* wh, float bb,
    float kmul, float vm, float va, const int* pidx)
{
  RowP p[8];
  #pragma unroll
  for (int k = 0; k < 8; ++k) p[k] = loadrow_p(src0 + k * sstep);
  const unsigned* lp = src0 + 8 * sstep;
  float c = 0.f, h = 0.f;
  float hall[5] = {0.f, 0.f, 0.f, 0.f, 0.f};
  unsigned* dp = dst0;
  for (int tt = 0; tt < T_ - 8; tt += 8) {
    #pragma unroll
    for (int j = 0; j < 8; ++j) {
      float xv[12];
      unpack_row(p[j], xv);
      cell_step<12>(xv, wi, wh, bb, kmul, vm, va, pidx, c, h, hall);
      if constexpr (STORE) { if (doStore) store_row(dp, hall); dp += dstep; }
      p[j] = loadrow_p(lp); lp += sstep;
    }
  }
  #pragma unroll
  for (int j = 0; j < 8; ++j) {
    float xv[12];
    unpack_row(p[j], xv);
    cell_step<12>(xv, wi, wh, bb, kmul, vm, va, pidx, c, h, hall);
    if constexpr (STORE) { if (doStore) store_row(dp, hall); dp += dstep; }
  }
  return h;
}

__device__ __forceinline__ void load_wi12(const float* Wip, float* wi) {
  #pragma unroll
  for (int k = 0; k < 5; ++k) wi[k] = Wip[k];
  wi[5] = 0.f;
  #pragma unroll
  for (int k = 0; k < 5; ++k) wi[6 + k] = Wip[5 + k];
  wi[11] = 0.f;
}

__global__ __launch_bounds__(256) void lstm_all(
    const float* __restrict__ x, const float* __restrict__ Wih0,
    const float* __restrict__ Wih, const float* __restrict__ Whh,
    const float* __restrict__ bias, const float* __restrict__ Wfc,
    const float* __restrict__ bfc, float* __restrict__ out,
    unsigned* __restrict__ ws, int b0, int nb)
{
  __shared__ float hlast[6][2][5];   // per-block: 6 batch x 2 dirs x H

  const int tid  = threadIdx.x;
  const int lane = tid & 63;
  const int wave = tid >> 6;
  const int giw  = lane / 20;          // group within wave: 0..2 (3 = idle lanes 60-63)
  const int q    = lane % 20;
  const int u    = q >> 2;
  const int g    = q & 3;
  const int row  = g * 5 + u;          // gate-matrix row (i:0-4, f:5-9, g:10-14, o:15-19)
  const int gl   = wave * 3 + (giw < 3 ? giw : 2);
  const int gid  = blockIdx.x * 12 + gl;
  const bool grpactive = (giw < 3) && (gid < 2 * nb);
  const int d    = gid & 1;
  const int bloc = gid >> 1;
  const int blocsafe = (bloc < nb) ? bloc : (nb - 1);
  const int babs = b0 + blocsafe;      // absolute batch index

  const int grpbase = (lane / 20) * 20;
  int pidx[5];
  #pragma unroll
  for (int k = 0; k < 5; ++k) pidx[k] = (grpbase + 4 * k) << 2;

  const float LOG2E = 1.4426950408889634f;
  const float kmul = (g == 2) ? (-2.0f * LOG2E) : (-LOG2E);
  const float vm   = (g == 2) ? 2.0f : 1.0f;
  const float va   = (g == 2) ? -1.0f : 0.0f;

  unsigned* S0 = ws;
  unsigned* S1 = ws + (size_t)nb * T_ * ROWDW;

  const bool doStore = (q == 0) && grpactive;   // one lane per chain writes the row
  const size_t rowbase = (size_t)blocsafe * T_ * ROWDW;
  const size_t t0off   = d ? (size_t)(T_ - 1) * ROWDW : 0;
  const int sstep = d ? -ROWDW : ROWDW;
  const int dhalf = 3 * d;             // dword offset of this dir's half-row

  float wh[5], bb;

  // ---------------- layer 0 (input width 2, f32 x) ----------------
  {
    float wi[2];
    const float* Wip = Wih0 + ((size_t)d * 20 + row) * 2;
    wi[0] = Wip[0]; wi[1] = Wip[1];
    const float* Whp = Whh + ((size_t)d * 20 + row) * 5;
    #pragma unroll
    for (int k = 0; k < 5; ++k) wh[k] = Whp[k];
    bb = bias[(size_t)d * 20 + row];
    const float* src0 = x + ((size_t)babs * T_ + (d ? (T_ - 1) : 0)) * 2;
    scan_l0(src0, d ? -2 : 2,
            S0 + rowbase + t0off + dhalf, sstep, doStore,
            wi, wh, bb, kmul, vm, va, pidx);
  }
  __syncthreads();

  // ---------------- layers 1..3 (packed input width 12) ----------------
  for (int l = 1; l < 4; ++l) {
    float wi[12];
    load_wi12(Wih + (((size_t)(l - 1) * 2 + d) * 20 + row) * 10, wi);
    const float* Whp = Whh + (((size_t)l * 2 + d) * 20 + row) * 5;
    #pragma unroll
    for (int k = 0; k < 5; ++k) wh[k] = Whp[k];
    bb = bias[((size_t)l * 2 + d) * 20 + row];
    const unsigned* src = (l & 1) ? S0 : S1;
    unsigned*       dst = (l & 1) ? S1 : S0;
    scan_packed<true>(src + rowbase + t0off, sstep,
                      dst + rowbase + t0off + dhalf, sstep, doStore,
                      wi, wh, bb, kmul, vm, va, pidx);
    __syncthreads();
  }

  // ---------------- layer 4: fwd = full scan (no stores); bwd = 1 step at t=T-1 ----------------
  {
    float wi[12];
    load_wi12(Wih + (((size_t)3 * 2 + d) * 20 + row) * 10, wi);
    const float* Whp = Whh + (((size_t)4 * 2 + d) * 20 + row) * 5;
    #pragma unroll
    for (int k = 0; k < 5; ++k) wh[k] = Whp[k];
    bb = bias[((size_t)4 * 2 + d) * 20 + row];

    float hfin;
    if (d == 0) {
      hfin = scan_packed<false>(S1 + rowbase, ROWDW, nullptr, 0, false,
                                wi, wh, bb, kmul, vm, va, pidx);
    } else {
      float xv[12];
      RowP r = loadrow_p(S1 + rowbase + (size_t)(T_ - 1) * ROWDW);
      unpack_row(r, xv);
      float cc = 0.f, hh = 0.f;
      float hall0[5] = {0.f, 0.f, 0.f, 0.f, 0.f};
      cell_step<12>(xv, wi, wh, bb, kmul, vm, va, pidx, cc, hh, hall0);
      hfin = hh;
    }
    if ((g == 0) && grpactive) hlast[gl >> 1][d][u] = hfin;  // 5 lanes store h_u
  }
  __syncthreads();

  // ---------------- fused FC: out[b] = hlast[b] @ Wfc^T + bfc ----------------
  if (tid < 12) {
    const int bl = tid >> 1, o = tid & 1;
    if (blockIdx.x * 6 + bl < nb) {
      const int gb = b0 + blockIdx.x * 6 + bl;
      float a = bfc[o];
      #pragma unroll
      for (int cix = 0; cix < 10; ++cix)
        a = fmaf(hlast[bl][cix / 5][cix % 5], Wfc[o * 10 + cix], a);
      out[gb * 2 + o] = a;
    }
  }
}

extern "C" void kernel_launch(void* const* d_in, const int* in_sizes, int n_in,
                              void* d_out, int out_size, void* d_ws, size_t ws_size,
                              hipStream_t stream) {
  (void)in_sizes; (void)n_in; (void)out_size;
  const float* x    = (const float*)d_in[0];
  const float* Wih0 = (const float*)d_in[1];
  const float* Wih  = (const float*)d_in[2];
  const float* Whh  = (const float*)d_in[3];
  const float* bias = (const float*)d_in[4];
  const float* Wfc  = (const float*)d_in[5];
  const float* bfc  = (const float*)d_in[6];
  float* out = (float*)d_out;
  unsigned* ws = (unsigned*)d_ws;

  // Chunk the batch if ws can't hold 2 ping-pong buffers of [nb][T][ROWDW] dwords.
  const size_t perBatch = (size_t)2 * T_ * ROWDW * sizeof(unsigned);  // 24576 B
  int nbmax = (int)(ws_size / perBatch);
  if (nbmax > B_) nbmax = B_;
  if (nbmax < 1)  nbmax = 1;

  for (int b0 = 0; b0 < B_; b0 += nbmax) {
    int nb = B_ - b0 < nbmax ? B_ - b0 : nbmax;
    dim3 grid((2 * nb + 11) / 12);
    dim3 block(256);
    lstm_all<<<grid, block, 0, stream>>>(x, Wih0, Wih, Whh, bias, Wfc, bfc,
                                         out, ws, b0, nb);
  }
}

// Round 3
// 511.375 us; speedup vs baseline: 1.3679x; 1.2006x over previous
//
#include <hip/hip_runtime.h>

#define T_ 512
#define B_ 2048
#define ROWDW 6      // dwords per packed inter-layer row (12 bf16, 24B)
#define ROWSH 12     // shorts per row
#define TANH_K (-2.8853900817779268f)   // -2*log2(e)

__device__ __forceinline__ float lo16(unsigned d) { return __int_as_float((int)(d << 16)); }
__device__ __forceinline__ float hi16(unsigned d) { return __int_as_float((int)(d & 0xFFFF0000u)); }

__device__ __forceinline__ unsigned bfr(float f) {   // f32 -> bf16 bits, RNE
  unsigned u = __float_as_uint(f);
  return (u + 0x7FFFu + ((u >> 16) & 1u)) >> 16;
}

template<int CTRL>
__device__ __forceinline__ float qb(float v) {
  // quad_perm DPP broadcast of one lane within each 4-lane quad
  return __int_as_float(__builtin_amdgcn_mov_dpp(__float_as_int(v), CTRL, 0xF, 0xF, true));
}

struct RowP { unsigned d[6]; };

__device__ __forceinline__ RowP loadrow_p(const unsigned* p) {
  RowP r;
  const uint2 a = *(const uint2*)p;
  const uint2 b = *(const uint2*)(p + 2);
  const uint2 c = *(const uint2*)(p + 4);
  r.d[0]=a.x; r.d[1]=a.y; r.d[2]=b.x; r.d[3]=b.y; r.d[4]=c.x; r.d[5]=c.y;
  return r;
}

// Input projection for a packed row: pre = bbk + sum wi[k]*x[k] over the 10
// real columns (cols 0-4 = dwords 0-2 lo/hi, cols 6-10 = dwords 3-5; pads skipped).
__device__ __forceinline__ float proj12(const RowP& r, const float* wi, float bbk) {
  float a = bbk, b = 0.f;
  a = fmaf(wi[0], lo16(r.d[0]), a);
  b = fmaf(wi[1], hi16(r.d[0]), b);
  a = fmaf(wi[2], lo16(r.d[1]), a);
  b = fmaf(wi[3], hi16(r.d[1]), b);
  a = fmaf(wi[4], lo16(r.d[2]), a);
  b = fmaf(wi[5], lo16(r.d[3]), b);
  a = fmaf(wi[6], hi16(r.d[3]), a);
  b = fmaf(wi[7], lo16(r.d[4]), b);
  a = fmaf(wi[8], hi16(r.d[4]), a);
  b = fmaf(wi[9], lo16(r.d[5]), b);
  return a + b;
}

// Serial recurrent step. pre already includes bias and the kmul gate-scale
// folded in (whk likewise pre-scaled). Lane q=4u+g owns gate g of unit u.
__device__ __forceinline__ void recur(float pre, const float* whk, float vm, float va,
                                      const int* pidx, float& c, float& h, float* hall) {
  float A  = fmaf(whk[1], hall[1], fmaf(whk[0], hall[0], pre));
  float Bv = fmaf(whk[4], hall[4], fmaf(whk[3], hall[3], whk[2] * hall[2]));
  const float acc = A + Bv;                                  // = -x*log2e (or -2x*log2e)
  const float s   = __builtin_amdgcn_rcpf(1.0f + __builtin_amdgcn_exp2f(acc));
  const float val = fmaf(s, vm, va);                         // sigmoid, or tanh=2s-1
  const float iv = qb<0x00>(val);
  const float fv = qb<0x55>(val);
  const float gv = qb<0xAA>(val);
  const float ov = qb<0xFF>(val);
  c = fmaf(fv, c, iv * gv);
  const float tc = fmaf(__builtin_amdgcn_rcpf(1.0f + __builtin_amdgcn_exp2f(c * TANH_K)), 2.0f, -1.0f);
  h = ov * tc;
  const int hb = __float_as_int(h);
  #pragma unroll
  for (int u = 0; u < 5; ++u)
    hall[u] = __int_as_float(__builtin_amdgcn_ds_bpermute(pidx[u], hb));
}

// Packed-input scan (layers 1..4). 8-slot pipeline: pre[j] consumed at step t,
// refilled from p[j] (row t+8, loaded 8 steps earlier), then row t+16 load issued.
// The proj+load sit in the ds_bpermute shadow. Store: 5 lanes (g==0) scatter
// their own h as bf16 shorts -> no dependency on bpermute results.
template<bool STORE>
__device__ __forceinline__ float scan12(const unsigned* src, int sstep,
    unsigned short* dsth, int dstep, bool doStore,
    const float* wi, const float* whk, float bbk, float vm, float va,
    const int* pidx)
{
  RowP p[8]; float pre[8];
  #pragma unroll
  for (int k = 0; k < 8; ++k) p[k] = loadrow_p(src + k * sstep);
  #pragma unroll
  for (int k = 0; k < 8; ++k) pre[k] = proj12(p[k], wi, bbk);
  #pragma unroll
  for (int k = 0; k < 8; ++k) p[k] = loadrow_p(src + (8 + k) * sstep);
  const unsigned* lp = src + 16 * sstep;
  float c = 0.f, h = 0.f;
  float hall[5] = {0.f, 0.f, 0.f, 0.f, 0.f};
  for (int tt = 0; tt < T_ - 16; tt += 8) {
    #pragma unroll
    for (int j = 0; j < 8; ++j) {
      recur(pre[j], whk, vm, va, pidx, c, h, hall);
      if constexpr (STORE) { if (doStore) *dsth = (unsigned short)bfr(h); dsth += dstep; }
      pre[j] = proj12(p[j], wi, bbk);
      p[j] = loadrow_p(lp); lp += sstep;
    }
  }
  #pragma unroll
  for (int j = 0; j < 8; ++j) {   // rows T-16..T-9; refill from rows T-8..T-1
    recur(pre[j], whk, vm, va, pidx, c, h, hall);
    if constexpr (STORE) { if (doStore) *dsth = (unsigned short)bfr(h); dsth += dstep; }
    pre[j] = proj12(p[j], wi, bbk);
  }
  #pragma unroll
  for (int j = 0; j < 8; ++j) {   // rows T-8..T-1
    recur(pre[j], whk, vm, va, pidx, c, h, hall);
    if constexpr (STORE) { if (doStore) *dsth = (unsigned short)bfr(h); dsth += dstep; }
  }
  return h;
}

// Layer-0 scan: f32 input, width 2.
__device__ __forceinline__ void scan2(const float* src, int sstep,
    unsigned short* dsth, int dstep, bool doStore,
    const float* wi, const float* whk, float bbk, float vm, float va,
    const int* pidx)
{
  float2 p[8]; float pre[8];
  #pragma unroll
  for (int k = 0; k < 8; ++k) p[k] = *(const float2*)(src + k * sstep);
  #pragma unroll
  for (int k = 0; k < 8; ++k) pre[k] = fmaf(wi[1], p[k].y, fmaf(wi[0], p[k].x, bbk));
  #pragma unroll
  for (int k = 0; k < 8; ++k) p[k] = *(const float2*)(src + (8 + k) * sstep);
  const float* lp = src + 16 * sstep;
  float c = 0.f, h = 0.f;
  float hall[5] = {0.f, 0.f, 0.f, 0.f, 0.f};
  for (int tt = 0; tt < T_ - 16; tt += 8) {
    #pragma unroll
    for (int j = 0; j < 8; ++j) {
      recur(pre[j], whk, vm, va, pidx, c, h, hall);
      if (doStore) *dsth = (unsigned short)bfr(h);
      dsth += dstep;
      pre[j] = fmaf(wi[1], p[j].y, fmaf(wi[0], p[j].x, bbk));
      p[j] = *(const float2*)lp; lp += sstep;
    }
  }
  #pragma unroll
  for (int j = 0; j < 8; ++j) {
    recur(pre[j], whk, vm, va, pidx, c, h, hall);
    if (doStore) *dsth = (unsigned short)bfr(h);
    dsth += dstep;
    pre[j] = fmaf(wi[1], p[j].y, fmaf(wi[0], p[j].x, bbk));
  }
  #pragma unroll
  for (int j = 0; j < 8; ++j) {
    recur(pre[j], whk, vm, va, pidx, c, h, hall);
    if (doStore) *dsth = (unsigned short)bfr(h);
    dsth += dstep;
  }
}

__global__ __launch_bounds__(256) void lstm_all(
    const float* __restrict__ x, const float* __restrict__ Wih0,
    const float* __restrict__ Wih, const float* __restrict__ Whh,
    const float* __restrict__ bias, const float* __restrict__ Wfc,
    const float* __restrict__ bfc, float* __restrict__ out,
    unsigned* __restrict__ ws, int b0, int nb)
{
  __shared__ float hlast[6][2][5];   // per-block: 6 batch x 2 dirs x H

  const int tid  = threadIdx.x;
  const int lane = tid & 63;
  const int wave = tid >> 6;
  const int giw  = lane / 20;          // group within wave: 0..2 (3 = idle lanes 60-63)
  const int q    = lane % 20;
  const int u    = q >> 2;
  const int g    = q & 3;
  const int row  = g * 5 + u;          // gate-matrix row (i:0-4, f:5-9, g:10-14, o:15-19)
  const int gl   = wave * 3 + (giw < 3 ? giw : 2);
  const int gid  = blockIdx.x * 12 + gl;
  const bool grpactive = (giw < 3) && (gid < 2 * nb);
  const int d    = gid & 1;
  const int bloc = gid >> 1;
  const int blocsafe = (bloc < nb) ? bloc : (nb - 1);
  const int babs = b0 + blocsafe;      // absolute batch index

  const int grpbase = (lane / 20) * 20;
  int pidx[5];
  #pragma unroll
  for (int k = 0; k < 5; ++k) pidx[k] = (grpbase + 4 * k) << 2;

  const float LOG2E = 1.4426950408889634f;
  const float km = (g == 2) ? (-2.0f * LOG2E) : (-LOG2E);   // folded into wi/wh/b
  const float vm = (g == 2) ? 2.0f : 1.0f;
  const float va = (g == 2) ? -1.0f : 0.0f;

  unsigned* S0 = ws;
  unsigned* S1 = ws + (size_t)nb * T_ * ROWDW;

  const bool doStore = (g == 0) && grpactive;   // 5 lanes/group scatter bf16 shorts
  const size_t rowdw = (size_t)blocsafe * T_ * ROWDW;      // dword base of this batch
  const size_t rowsh = (size_t)blocsafe * T_ * ROWSH;      // short base
  const size_t t0dw  = d ? (size_t)(T_ - 1) * ROWDW : 0;
  const size_t t0sh  = d ? (size_t)(T_ - 1) * ROWSH : 0;
  const int sstep = d ? -ROWDW : ROWDW;
  const int dstep = d ? -ROWSH : ROWSH;
  const int dcol  = 6 * d + u;         // this lane's bf16 column in the row

  float whk[5], bbk;

  // ---------------- layer 0 (input width 2, f32 x) ----------------
  {
    float wik[2];
    const float* Wip = Wih0 + ((size_t)d * 20 + row) * 2;
    wik[0] = Wip[0] * km; wik[1] = Wip[1] * km;
    const float* Whp = Whh + ((size_t)d * 20 + row) * 5;
    #pragma unroll
    for (int k = 0; k < 5; ++k) whk[k] = Whp[k] * km;
    bbk = bias[(size_t)d * 20 + row] * km;
    const float* src0 = x + ((size_t)babs * T_ + (d ? (T_ - 1) : 0)) * 2;
    scan2(src0, d ? -2 : 2,
          (unsigned short*)S0 + rowsh + t0sh + dcol, dstep, doStore,
          wik, whk, bbk, vm, va, pidx);
  }
  __syncthreads();

  // ---------------- layers 1..3 (packed input width 10) ----------------
  for (int l = 1; l < 4; ++l) {
    float wik[10];
    const float* Wip = Wih + (((size_t)(l - 1) * 2 + d) * 20 + row) * 10;
    #pragma unroll
    for (int k = 0; k < 10; ++k) wik[k] = Wip[k] * km;
    const float* Whp = Whh + (((size_t)l * 2 + d) * 20 + row) * 5;
    #pragma unroll
    for (int k = 0; k < 5; ++k) whk[k] = Whp[k] * km;
    bbk = bias[((size_t)l * 2 + d) * 20 + row] * km;
    const unsigned* src = (l & 1) ? S0 : S1;
    unsigned*       dst = (l & 1) ? S1 : S0;
    scan12<true>(src + rowdw + t0dw, sstep,
                 (unsigned short*)dst + rowsh + t0sh + dcol, dstep, doStore,
                 wik, whk, bbk, vm, va, pidx);
    __syncthreads();
  }

  // ---------------- layer 4: fwd = full scan (no stores); bwd = 1 step at t=T-1 ----------------
  {
    float wik[10];
    const float* Wip = Wih + (((size_t)3 * 2 + d) * 20 + row) * 10;
    #pragma unroll
    for (int k = 0; k < 10; ++k) wik[k] = Wip[k] * km;
    const float* Whp = Whh + (((size_t)4 * 2 + d) * 20 + row) * 5;
    #pragma unroll
    for (int k = 0; k < 5; ++k) whk[k] = Whp[k] * km;
    bbk = bias[((size_t)4 * 2 + d) * 20 + row] * km;

    float hfin;
    if (d == 0) {
      hfin = scan12<false>(S1 + rowdw, ROWDW, nullptr, 0, false,
                           wik, whk, bbk, vm, va, pidx);
    } else {
      RowP r = loadrow_p(S1 + rowdw + (size_t)(T_ - 1) * ROWDW);
      float pre0 = proj12(r, wik, bbk);
      float cc = 0.f, hh = 0.f;
      float hall0[5] = {0.f, 0.f, 0.f, 0.f, 0.f};
      recur(pre0, whk, vm, va, pidx, cc, hh, hall0);
      hfin = hh;
    }
    if ((g == 0) && grpactive) hlast[gl >> 1][d][u] = hfin;  // 5 lanes store h_u
  }
  __syncthreads();

  // ---------------- fused FC: out[b] = hlast[b] @ Wfc^T + bfc ----------------
  if (tid < 12) {
    const int bl = tid >> 1, o = tid & 1;
    if (blockIdx.x * 6 + bl < nb) {
      const int gb = b0 + blockIdx.x * 6 + bl;
      float a = bfc[o];
      #pragma unroll
      for (int cix = 0; cix < 10; ++cix)
        a = fmaf(hlast[bl][cix / 5][cix % 5], Wfc[o * 10 + cix], a);
      out[gb * 2 + o] = a;
    }
  }
}

extern "C" void kernel_launch(void* const* d_in, const int* in_sizes, int n_in,
                              void* d_out, int out_size, void* d_ws, size_t ws_size,
                              hipStream_t stream) {
  (void)in_sizes; (void)n_in; (void)out_size;
  const float* x    = (const float*)d_in[0];
  const float* Wih0 = (const float*)d_in[1];
  const float* Wih  = (const float*)d_in[2];
  const float* Whh  = (const float*)d_in[3];
  const float* bias = (const float*)d_in[4];
  const float* Wfc  = (const float*)d_in[5];
  const float* bfc  = (const float*)d_in[6];
  float* out = (float*)d_out;
  unsigned* ws = (unsigned*)d_ws;

  // Chunk the batch if ws can't hold 2 ping-pong buffers of [nb][T][ROWDW] dwords.
  const size_t perBatch = (size_t)2 * T_ * ROWDW * sizeof(unsigned);  // 24576 B
  int nbmax = (int)(ws_size / perBatch);
  if (nbmax > B_) nbmax = B_;
  if (nbmax < 1)  nbmax = 1;

  for (int b0 = 0; b0 < B_; b0 += nbmax) {
    int nb = B_ - b0 < nbmax ? B_ - b0 : nbmax;
    dim3 grid((2 * nb + 11) / 12);
    dim3 block(256);
    lstm_all<<<grid, block, 0, stream>>>(x, Wih0, Wih, Whh, bias, Wfc, bfc,
                                         out, ws, b0, nb);
  }
}

// Round 5
// 488.222 us; speedup vs baseline: 1.4327x; 1.0474x over previous
//
#include <hip/hip_runtime.h>

#define T_ 512
#define B_ 2048
#define ROWDW 6      // dwords per packed inter-layer row (12 bf16 cols, 24 B)
#define TANH_K (-2.8853900817779268f)   // -2*log2(e)

// DPP ctrl encodings (gfx9/CDNA):
//   0x00-0xFF quad_perm | 0x120+n row_ror:n | 0x140 ROW_MIRROR | 0x141 ROW_HALF_MIRROR
#define DPP_ROW_ROR8        0x128   // lane^8  within 16-lane row
#define DPP_ROW_MIRROR      0x140   // lane^15 within 16-lane row
#define DPP_ROW_HALF_MIRROR 0x141   // lane^7  within 16-lane row

__device__ __forceinline__ float sig2(float y) {           // 1/(1+exp2(y))
  return __builtin_amdgcn_rcpf(1.0f + __builtin_amdgcn_exp2f(y));
}

template<int CTRL>
__device__ __forceinline__ float dppf(float v) {
  return __int_as_float(__builtin_amdgcn_mov_dpp(__float_as_int(v), CTRL, 0xF, 0xF, true));
}

__device__ __forceinline__ float lo16(unsigned d) { return __int_as_float((int)(d << 16)); }
__device__ __forceinline__ float hi16(unsigned d) { return __int_as_float((int)(d & 0xFFFF0000u)); }

__device__ __forceinline__ unsigned bfr(float f) {   // f32 -> bf16 bits, RNE
  unsigned u = __float_as_uint(f);
  return (u + 0x7FFFu + ((u >> 16) & 1u)) >> 16;
}

struct RowP { unsigned d[6]; };
struct Pre2 { float a, b; };

__device__ __forceinline__ RowP loadrow_p(const unsigned* p) {
  RowP r;
  const uint2 a = *(const uint2*)p;
  const uint2 b = *(const uint2*)(p + 2);
  const uint2 c = *(const uint2*)(p + 4);
  r.d[0]=a.x; r.d[1]=a.y; r.d[2]=b.x; r.d[3]=b.y; r.d[4]=c.x; r.d[5]=c.y;
  return r;
}

// Dual input projection: row A (own unit p, gate g) and row B (unit 4, gate g).
// Real cols: 0-4 (dwords 0-2) fwd half, 6-10 (dwords 3-5) bwd half; pads skipped.
__device__ __forceinline__ Pre2 proj_dual(const RowP& r,
    const float* wiA, const float* wiB, float bbA, float bbB) {
  const float x0=lo16(r.d[0]), x1=hi16(r.d[0]), x2=lo16(r.d[1]), x3=hi16(r.d[1]), x4=lo16(r.d[2]);
  const float x5=lo16(r.d[3]), x6=hi16(r.d[3]), x7=lo16(r.d[4]), x8=hi16(r.d[4]), x9=lo16(r.d[5]);
  float a0=bbA, a1=0.f, b0=bbB, b1=0.f;
  a0=fmaf(wiA[0],x0,a0); a1=fmaf(wiA[1],x1,a1);
  a0=fmaf(wiA[2],x2,a0); a1=fmaf(wiA[3],x3,a1);
  a0=fmaf(wiA[4],x4,a0); a1=fmaf(wiA[5],x5,a1);
  a0=fmaf(wiA[6],x6,a0); a1=fmaf(wiA[7],x7,a1);
  a0=fmaf(wiA[8],x8,a0); a1=fmaf(wiA[9],x9,a1);
  b0=fmaf(wiB[0],x0,b0); b1=fmaf(wiB[1],x1,b1);
  b0=fmaf(wiB[2],x2,b0); b1=fmaf(wiB[3],x3,b1);
  b0=fmaf(wiB[4],x4,b0); b1=fmaf(wiB[5],x5,b1);
  b0=fmaf(wiB[6],x6,b0); b1=fmaf(wiB[7],x7,b1);
  b0=fmaf(wiB[8],x8,b0); b1=fmaf(wiB[9],x9,b1);
  Pre2 o; o.a = a0+a1; o.b = b0+b1; return o;
}

// One recurrent step for a 16-lane chain. Lane = 4p+g: row A = gate g of unit p,
// row B = gate g of unit 4 (computed redundantly/identically in every quad).
// h slots: h0s = h_{p}, h1s = h_{p^1}, h2s = h_{p^2}, h3s = h_{p^3}; h4 lane-local.
// wsA/wsB are slot-permuted recurrent weights (pre-scaled by kmul).
__device__ __forceinline__ void recur_dual(float preA, float preB,
    const float* wsA, const float* wsB, float vm, float va,
    float& c, float& c4, float& h0s, float& h1s, float& h2s, float& h3s, float& h4)
{
  const float a0 = fmaf(wsA[1], h1s, fmaf(wsA[0], h0s, preA));
  const float a1 = fmaf(wsA[4], h4,  fmaf(wsA[3], h3s, wsA[2] * h2s));
  const float b0 = fmaf(wsB[1], h1s, fmaf(wsB[0], h0s, preB));
  const float b1 = fmaf(wsB[4], h4,  fmaf(wsB[3], h3s, wsB[2] * h2s));
  const float vA = fmaf(sig2(a0 + a1), vm, va);   // sigmoid, or tanh = 2s-1
  const float vB = fmaf(sig2(b0 + b1), vm, va);
  const float ivA = dppf<0x00>(vA), fvA = dppf<0x55>(vA), gvA = dppf<0xAA>(vA), ovA = dppf<0xFF>(vA);
  const float ivB = dppf<0x00>(vB), fvB = dppf<0x55>(vB), gvB = dppf<0xAA>(vB), ovB = dppf<0xFF>(vB);
  c  = fmaf(fvA, c,  ivA * gvA);
  c4 = fmaf(fvB, c4, ivB * gvB);
  const float h = fmaf(sig2(c * TANH_K), 2.0f * ovA, -ovA);   // ov*tanh(c)
  h4            = fmaf(sig2(c4 * TANH_K), 2.0f * ovB, -ovB);
  h0s = h;
  h1s = dppf<DPP_ROW_HALF_MIRROR>(h);   // lane^7  -> unit p^1 (h is quad-uniform)
  h2s = dppf<DPP_ROW_ROR8>(h);          // lane^8  -> unit p^2
  h3s = dppf<DPP_ROW_MIRROR>(h);        // lane^15 -> unit p^3
}

#define EMIT_STORE()                                              \
  if constexpr (STORE) {                                          \
    if (doStore) {                                                \
      dp[i0]     = bfr(h0s) | (bfr(h1s) << 16);                   \
      dp[i0 + 1] = bfr(h2s) | (bfr(h3s) << 16);                   \
      ((unsigned short*)dp)[ish] = (unsigned short)bfr(h4);       \
    }                                                             \
    dp += sstep;                                                  \
  }

// Packed-input scan (layers 1..4), 8-slot software pipeline.
template<bool STORE>
__device__ __forceinline__ void scan_dual(const unsigned* src, int sstep,
    unsigned* dst, int dd, bool doStore,
    const float* wiA, const float* wiB, float bbA, float bbB,
    const float* wsA, const float* wsB, float vm, float va,
    float& c, float& c4, float& h0s, float& h1s, float& h2s, float& h3s, float& h4)
{
  RowP p_[8]; Pre2 pre[8];
  #pragma unroll
  for (int k = 0; k < 8; ++k) p_[k] = loadrow_p(src + k * sstep);
  #pragma unroll
  for (int k = 0; k < 8; ++k) pre[k] = proj_dual(p_[k], wiA, wiB, bbA, bbB);
  #pragma unroll
  for (int k = 0; k < 8; ++k) p_[k] = loadrow_p(src + (8 + k) * sstep);
  const unsigned* lp = src + 16 * sstep;
  c = 0.f; c4 = 0.f; h0s = h1s = h2s = h3s = h4 = 0.f;
  unsigned* dp = dst;
  const int i0 = 3 * dd, ish = 6 * dd + 4;
  for (int tt = 0; tt < T_ - 16; tt += 8) {
    #pragma unroll
    for (int j = 0; j < 8; ++j) {
      recur_dual(pre[j].a, pre[j].b, wsA, wsB, vm, va, c, c4, h0s, h1s, h2s, h3s, h4);
      EMIT_STORE()
      pre[j] = proj_dual(p_[j], wiA, wiB, bbA, bbB);
      p_[j] = loadrow_p(lp); lp += sstep;
    }
  }
  #pragma unroll
  for (int j = 0; j < 8; ++j) {     // steps T-16..T-9, refill pre from last rows
    recur_dual(pre[j].a, pre[j].b, wsA, wsB, vm, va, c, c4, h0s, h1s, h2s, h3s, h4);
    EMIT_STORE()
    pre[j] = proj_dual(p_[j], wiA, wiB, bbA, bbB);
  }
  #pragma unroll
  for (int j = 0; j < 8; ++j) {     // steps T-8..T-1
    recur_dual(pre[j].a, pre[j].b, wsA, wsB, vm, va, c, c4, h0s, h1s, h2s, h3s, h4);
    EMIT_STORE()
  }
}

// Layer-0 scan: f32 input, width 2.
template<bool STORE>
__device__ __forceinline__ void scan2_dual(const float* src, int sstep,
    unsigned* dst, int dsteprow, int dd, bool doStore,
    const float* wiA, const float* wiB, float bbA, float bbB,
    const float* wsA, const float* wsB, float vm, float va,
    float& c, float& c4, float& h0s, float& h1s, float& h2s, float& h3s, float& h4)
{
  float2 p_[8]; Pre2 pre[8];
  #pragma unroll
  for (int k = 0; k < 8; ++k) p_[k] = *(const float2*)(src + k * sstep);
  #pragma unroll
  for (int k = 0; k < 8; ++k) {
    pre[k].a = fmaf(wiA[1], p_[k].y, fmaf(wiA[0], p_[k].x, bbA));
    pre[k].b = fmaf(wiB[1], p_[k].y, fmaf(wiB[0], p_[k].x, bbB));
  }
  #pragma unroll
  for (int k = 0; k < 8; ++k) p_[k] = *(const float2*)(src + (8 + k) * sstep);
  const float* lp = src + 16 * sstep;
  c = 0.f; c4 = 0.f; h0s = h1s = h2s = h3s = h4 = 0.f;
  unsigned* dp = dst;
  const int sstep_ = dsteprow;
  const int i0 = 3 * dd, ish = 6 * dd + 4;
  #define EMIT_STORE0()                                             \
    if constexpr (STORE) {                                          \
      if (doStore) {                                                \
        dp[i0]     = bfr(h0s) | (bfr(h1s) << 16);                   \
        dp[i0 + 1] = bfr(h2s) | (bfr(h3s) << 16);                   \
        ((unsigned short*)dp)[ish] = (unsigned short)bfr(h4);       \
      }                                                             \
      dp += sstep_;                                                 \
    }
  for (int tt = 0; tt < T_ - 16; tt += 8) {
    #pragma unroll
    for (int j = 0; j < 8; ++j) {
      recur_dual(pre[j].a, pre[j].b, wsA, wsB, vm, va, c, c4, h0s, h1s, h2s, h3s, h4);
      EMIT_STORE0()
      pre[j].a = fmaf(wiA[1], p_[j].y, fmaf(wiA[0], p_[j].x, bbA));
      pre[j].b = fmaf(wiB[1], p_[j].y, fmaf(wiB[0], p_[j].x, bbB));
      p_[j] = *(const float2*)lp; lp += sstep;
    }
  }
  #pragma unroll
  for (int j = 0; j < 8; ++j) {
    recur_dual(pre[j].a, pre[j].b, wsA, wsB, vm, va, c, c4, h0s, h1s, h2s, h3s, h4);
    EMIT_STORE0()
    pre[j].a = fmaf(wiA[1], p_[j].y, fmaf(wiA[0], p_[j].x, bbA));
    pre[j].b = fmaf(wiB[1], p_[j].y, fmaf(wiB[0], p_[j].x, bbB));
  }
  #pragma unroll
  for (int j = 0; j < 8; ++j) {
    recur_dual(pre[j].a, pre[j].b, wsA, wsB, vm, va, c, c4, h0s, h1s, h2s, h3s, h4);
    EMIT_STORE0()
  }
  #undef EMIT_STORE0
}

__global__ __launch_bounds__(256) void lstm_all(
    const float* __restrict__ x, const float* __restrict__ Wih0,
    const float* __restrict__ Wih, const float* __restrict__ Whh,
    const float* __restrict__ bias, const float* __restrict__ Wfc,
    const float* __restrict__ bfc, float* __restrict__ out,
    unsigned* __restrict__ ws, int b0, int nb)
{
  __shared__ float hlast[8][2][5];   // per-block: 8 batches x 2 dirs x H

  const int tid  = threadIdx.x;
  const int lane = tid & 63;
  const int wave = tid >> 6;
  const int cw   = lane >> 4;          // chain within wave: 0..3
  const int sub  = lane & 15;
  const int p    = sub >> 2;           // hidden unit (quad) 0..3
  const int g    = sub & 3;            // gate 0=i,1=f,2=g,3=o
  const int rowA = g * 5 + p;          // own gate-matrix row
  const int rowB = g * 5 + 4;          // unit-4 row (redundant in all quads)
  const int ch   = wave * 4 + cw;      // chain in block: 0..15
  const int dd   = ch & 1;             // direction
  const int blb  = ch >> 1;            // block-local batch 0..7
  const int bloc = blockIdx.x * 8 + blb;
  const bool active = (bloc < nb);
  const int blocsafe = active ? bloc : (nb - 1);
  const int babs = b0 + blocsafe;

  // slot unit indices for the DPP distribution
  const int i1 = p ^ 1, i2 = p ^ 2, i3 = p ^ 3;

  const float LOG2E = 1.4426950408889634f;
  const float km = (g == 2) ? (-2.0f * LOG2E) : (-LOG2E);   // folded into weights
  const float vm = (g == 2) ? 2.0f : 1.0f;
  const float va = (g == 2) ? -1.0f : 0.0f;

  unsigned* S0 = ws;
  unsigned* S1 = ws + (size_t)nb * T_ * ROWDW;

  const bool doStore = (sub == 0) && active;   // one lane per chain writes the half-row
  const size_t rowdw = (size_t)blocsafe * T_ * ROWDW;
  const size_t t0dw  = dd ? (size_t)(T_ - 1) * ROWDW : 0;
  const int sstep = dd ? -ROWDW : ROWDW;

  float wsA[5], wsB[5], bbA, bbB;
  float c, c4, h0s, h1s, h2s, h3s, h4;

  // ---------------- layer 0 (f32 x, width 2) ----------------
  {
    float wiA2[2], wiB2[2];
    const float* W0 = Wih0 + (size_t)dd * 20 * 2;
    wiA2[0] = W0[rowA*2+0] * km; wiA2[1] = W0[rowA*2+1] * km;
    wiB2[0] = W0[rowB*2+0] * km; wiB2[1] = W0[rowB*2+1] * km;
    const float* Whp = Whh + (size_t)dd * 20 * 5;
    wsA[0]=Whp[rowA*5+p]*km; wsA[1]=Whp[rowA*5+i1]*km; wsA[2]=Whp[rowA*5+i2]*km;
    wsA[3]=Whp[rowA*5+i3]*km; wsA[4]=Whp[rowA*5+4]*km;
    wsB[0]=Whp[rowB*5+p]*km; wsB[1]=Whp[rowB*5+i1]*km; wsB[2]=Whp[rowB*5+i2]*km;
    wsB[3]=Whp[rowB*5+i3]*km; wsB[4]=Whp[rowB*5+4]*km;
    bbA = bias[(size_t)dd * 20 + rowA] * km;
    bbB = bias[(size_t)dd * 20 + rowB] * km;
    const float* src0 = x + ((size_t)babs * T_ + (dd ? (T_ - 1) : 0)) * 2;
    scan2_dual<true>(src0, dd ? -2 : 2,
                     S0 + rowdw + t0dw, sstep, dd, doStore,
                     wiA2, wiB2, bbA, bbB, wsA, wsB, vm, va,
                     c, c4, h0s, h1s, h2s, h3s, h4);
  }
  __syncthreads();

  // ---------------- layers 1..3 (packed bf16 input) ----------------
  for (int l = 1; l < 4; ++l) {
    float wiA[10], wiB[10];
    const float* Wip = Wih + ((size_t)(l - 1) * 2 + dd) * 20 * 10;
    #pragma unroll
    for (int k = 0; k < 10; ++k) { wiA[k] = Wip[rowA*10+k] * km; wiB[k] = Wip[rowB*10+k] * km; }
    const float* Whp = Whh + ((size_t)l * 2 + dd) * 20 * 5;
    wsA[0]=Whp[rowA*5+p]*km; wsA[1]=Whp[rowA*5+i1]*km; wsA[2]=Whp[rowA*5+i2]*km;
    wsA[3]=Whp[rowA*5+i3]*km; wsA[4]=Whp[rowA*5+4]*km;
    wsB[0]=Whp[rowB*5+p]*km; wsB[1]=Whp[rowB*5+i1]*km; wsB[2]=Whp[rowB*5+i2]*km;
    wsB[3]=Whp[rowB*5+i3]*km; wsB[4]=Whp[rowB*5+4]*km;
    bbA = bias[((size_t)l * 2 + dd) * 20 + rowA] * km;
    bbB = bias[((size_t)l * 2 + dd) * 20 + rowB] * km;
    const unsigned* src = (l & 1) ? S0 : S1;
    unsigned*       dst = (l & 1) ? S1 : S0;
    scan_dual<true>(src + rowdw + t0dw, sstep,
                    dst + rowdw + t0dw, dd, doStore,
                    wiA, wiB, bbA, bbB, wsA, wsB, vm, va,
                    c, c4, h0s, h1s, h2s, h3s, h4);
    __syncthreads();
  }

  // ---------------- layer 4: fwd = full scan (no stores); bwd = 1 step ----------------
  {
    float wiA[10], wiB[10];
    const float* Wip = Wih + ((size_t)3 * 2 + dd) * 20 * 10;
    #pragma unroll
    for (int k = 0; k < 10; ++k) { wiA[k] = Wip[rowA*10+k] * km; wiB[k] = Wip[rowB*10+k] * km; }
    const float* Whp = Whh + ((size_t)4 * 2 + dd) * 20 * 5;
    wsA[0]=Whp[rowA*5+p]*km; wsA[1]=Whp[rowA*5+i1]*km; wsA[2]=Whp[rowA*5+i2]*km;
    wsA[3]=Whp[rowA*5+i3]*km; wsA[4]=Whp[rowA*5+4]*km;
    wsB[0]=Whp[rowB*5+p]*km; wsB[1]=Whp[rowB*5+i1]*km; wsB[2]=Whp[rowB*5+i2]*km;
    wsB[3]=Whp[rowB*5+i3]*km; wsB[4]=Whp[rowB*5+4]*km;
    bbA = bias[((size_t)4 * 2 + dd) * 20 + rowA] * km;
    bbB = bias[((size_t)4 * 2 + dd) * 20 + rowB] * km;

    if (dd == 0) {
      scan_dual<false>(S1 + rowdw, ROWDW, S1 + rowdw, 0, false,
                       wiA, wiB, bbA, bbB, wsA, wsB, vm, va,
                       c, c4, h0s, h1s, h2s, h3s, h4);
    } else {
      RowP r = loadrow_p(S1 + rowdw + (size_t)(T_ - 1) * ROWDW);
      Pre2 pr = proj_dual(r, wiA, wiB, bbA, bbB);
      c = 0.f; c4 = 0.f; h0s = h1s = h2s = h3s = h4 = 0.f;
      recur_dual(pr.a, pr.b, wsA, wsB, vm, va, c, c4, h0s, h1s, h2s, h3s, h4);
    }
    if (doStore) {
      // lane p0g0 slots: h0s=h0, h1s=h1, h2s=h2, h3s=h3, h4
      hlast[blb][dd][0] = h0s; hlast[blb][dd][1] = h1s;
      hlast[blb][dd][2] = h2s; hlast[blb][dd][3] = h3s;
      hlast[blb][dd][4] = h4;
    }
  }
  __syncthreads();

  // ---------------- fused FC: out[b] = hlast[b] @ Wfc^T + bfc ----------------
  if (tid < 16) {
    const int bl = tid >> 1, o = tid & 1;
    if (blockIdx.x * 8 + bl < nb) {
      const int gb = b0 + blockIdx.x * 8 + bl;
      float a = bfc[o];
      #pragma unroll
      for (int u = 0; u < 5; ++u) a = fmaf(hlast[bl][0][u], Wfc[o * 10 + u], a);
      #pragma unroll
      for (int u = 0; u < 5; ++u) a = fmaf(hlast[bl][1][u], Wfc[o * 10 + 5 + u], a);
      out[gb * 2 + o] = a;
    }
  }
}

extern "C" void kernel_launch(void* const* d_in, const int* in_sizes, int n_in,
                              void* d_out, int out_size, void* d_ws, size_t ws_size,
                              hipStream_t stream) {
  (void)in_sizes; (void)n_in; (void)out_size;
  const float* x    = (const float*)d_in[0];
  const float* Wih0 = (const float*)d_in[1];
  const float* Wih  = (const float*)d_in[2];
  const float* Whh  = (const float*)d_in[3];
  const float* bias = (const float*)d_in[4];
  const float* Wfc  = (const float*)d_in[5];
  const float* bfc  = (const float*)d_in[6];
  float* out = (float*)d_out;
  unsigned* ws = (unsigned*)d_ws;

  const size_t perBatch = (size_t)2 * T_ * ROWDW * sizeof(unsigned);  // 24576 B
  int nbmax = (int)(ws_size / perBatch);
  if (nbmax > B_) nbmax = B_;
  if (nbmax < 1)  nbmax = 1;

  for (int b0 = 0; b0 < B_; b0 += nbmax) {
    int nb = B_ - b0 < nbmax ? B_ - b0 : nbmax;
    dim3 grid((nb + 7) / 8);
    dim3 block(256);
    lstm_all<<<grid, block, 0, stream>>>(x, Wih0, Wih, Whh, bias, Wfc, bfc,
                                         out, ws, b0, nb);
  }
}